// Round 6
// baseline (8352.696 us; speedup 1.0000x reference)
//
#include <hip/hip_runtime.h>
#include <math.h>

#define NB   4096
#define HID  512
#define G4H  2048
#define EDIM 256
#define FINP 8
#define TSTEPS 64
#define FWIN 32

typedef __bf16 bf16;
typedef bf16  bf16x8 __attribute__((ext_vector_type(8)));
typedef float f32x4  __attribute__((ext_vector_type(4)));

__device__ __forceinline__ float sigf(float x) { return 1.0f / (1.0f + __expf(-x)); }
__device__ __forceinline__ float tanhf_(float x) { return 2.0f * sigf(2.0f * x) - 1.0f; }

__device__ __forceinline__ void gload16(const void* g, void* l) {
    __builtin_amdgcn_global_load_lds((const __attribute__((address_space(1))) void*)g,
                                     (__attribute__((address_space(3))) void*)l, 16, 0, 0);
}

// Bijective XCD-chunked swizzle (nwg % 8 == 0 for all our grids; gridDim.x==32)
__device__ __forceinline__ void swz32(int& bx, int& by) {
    int nwg  = (int)(gridDim.x * gridDim.y);
    int orig = (int)(blockIdx.x + blockIdx.y * gridDim.x);
    int swz  = (orig & 7) * (nwg >> 3) + (orig >> 3);
    bx = swz & 31;
    by = swz >> 5;
}

// ---------------------------------------------------------------------------
// 128x128-tile bf16 MFMA accumulate over npass*512 K.
// LDS layout (per 8KB buffer): 512 chunks of 16B, chunk c holds
//   A[row=(c>>6)*16+(c&15)][8 bf16 at koct=(c>>4)&3] -- fragment-major, so a
//   wave's frag read is base + lane*16 (contiguous 1KB, conflict-free) and
//   gload_lds dst stays linear (wave base + lane*16).
// Pipeline (m201 phase pattern): stage(s+1) -> vmcnt(4) -> s_barrier ->
//   ds_read+MFMA -> s_barrier. Prefetch has a full compute phase to land.
// 256 threads = 4 waves (2x2 of 64x64). A,W row-major ld=512.
// ---------------------------------------------------------------------------
__device__ __forceinline__ void gemm_acc(
    const bf16* __restrict__ A1, const bf16* __restrict__ W1,
    const bf16* __restrict__ A2, const bf16* __restrict__ W2, int npass,
    int m0, int n0, bf16 (&As)[2][4096], bf16 (&Ws)[2][4096], f32x4 (&acc)[4][4])
{
    const int tid  = threadIdx.x;
    const int lane = tid & 63;
    const int w    = tid >> 6;
    const int wr   = w >> 1, wc = w & 1;
    const int NK   = npass << 4;

    // staging: thread covers chunks tid and tid+256
    const int r0 = ((tid >> 6) << 4) + (tid & 15);
    const int o0 = ((tid >> 4) & 3) * 8;
    const int t1 = tid + 256;
    const int r1 = ((t1 >> 6) << 4) + (t1 & 15);
    const int o1 = ((t1 >> 4) & 3) * 8;

    auto stage = [&](int s, int b) {
        const bf16* A = (s < 16) ? A1 : A2;
        const bf16* W = (s < 16) ? W1 : W2;
        const int k0 = (s & 15) << 5;
        gload16(A + (size_t)(m0 + r0) * HID + k0 + o0, &As[b][tid * 8]);
        gload16(A + (size_t)(m0 + r1) * HID + k0 + o1, &As[b][(tid + 256) * 8]);
        gload16(W + (size_t)(n0 + r0) * HID + k0 + o0, &Ws[b][tid * 8]);
        gload16(W + (size_t)(n0 + r1) * HID + k0 + o1, &Ws[b][(tid + 256) * 8]);
    };

    stage(0, 0);
    asm volatile("s_waitcnt vmcnt(0)" ::: "memory");
    __builtin_amdgcn_s_barrier();
    int cur = 0;
    for (int s = 0; s < NK; ++s) {
        if (s + 1 < NK) {
            stage(s + 1, cur ^ 1);                     // prefetch flies across barrier
            asm volatile("s_waitcnt vmcnt(4)" ::: "memory");  // own buf[cur] loads done
        } else {
            asm volatile("s_waitcnt vmcnt(0)" ::: "memory");
        }
        __builtin_amdgcn_s_barrier();                  // everyone's buf[cur] loads done
        const bf16* abase = &As[cur][(wr << 2) * 512 + lane * 8];
        const bf16* bbase = &Ws[cur][(wc << 2) * 512 + lane * 8];
        bf16x8 af[4], bfr[4];
#pragma unroll
        for (int m = 0; m < 4; ++m) af[m] = *(const bf16x8*)(abase + m * 512);
#pragma unroll
        for (int n = 0; n < 4; ++n) bfr[n] = *(const bf16x8*)(bbase + n * 512);
#pragma unroll
        for (int m = 0; m < 4; ++m)
#pragma unroll
            for (int n = 0; n < 4; ++n)
                acc[m][n] = __builtin_amdgcn_mfma_f32_16x16x32_bf16(af[m], bfr[n], acc[m][n], 0, 0, 0);
        __builtin_amdgcn_s_barrier();                  // all done reading buf[cur]
        cur ^= 1;
    }
}

// ---------------------------------------------------------------------------
// LSTM epilogue. Weight rows pre-reordered: j_new = (hu>>4)*64 + gate*16 +
// (hu&15) -> wave's 4 N-frags are gates i,f,g,o of 16 hus (lane-local).
// ---------------------------------------------------------------------------
template<bool HASX>
__device__ __forceinline__ void lstm_epi(f32x4 (&acc)[4][4],
    const float* __restrict__ Wfc, const float* __restrict__ bias,
    const float* __restrict__ xA, int sx,
    float* __restrict__ cst, bf16* __restrict__ hdst, int m0, int n0)
{
    const int tid = threadIdx.x, lane = tid & 63, w = tid >> 6;
    const int wr = w >> 1, wc = w & 1, l16 = lane & 15, lq = lane >> 4;
    const int hu = (n0 >> 2) + wc * 16 + l16;
    const int jb = n0 + wc * 64 + l16;

    float bq[4];
    f32x4 wf0[4], wf1[4];
#pragma unroll
    for (int g = 0; g < 4; ++g) {
        bq[g] = bias[jb + g * 16];
        if constexpr (HASX) {
            const float* wrow = Wfc + (size_t)(jb + g * 16) * 8;
            wf0[g] = *(const f32x4*)wrow;
            wf1[g] = *(const f32x4*)(wrow + 4);
        }
    }
#pragma unroll
    for (int m = 0; m < 4; ++m) {
        const int rb = m0 + wr * 64 + m * 16 + lq * 4;
#pragma unroll
        for (int q = 0; q < 4; ++q) {
            const int r = rb + q;
            float d0 = 0.f, d1 = 0.f, d2 = 0.f, d3 = 0.f;
            if constexpr (HASX) {
                const float* xr = xA + (size_t)r * sx;
                f32x4 xv0 = *(const f32x4*)xr;
                f32x4 xv1 = *(const f32x4*)(xr + 4);
                f32x4 p0 = xv0 * wf0[0] + xv1 * wf1[0];
                f32x4 p1 = xv0 * wf0[1] + xv1 * wf1[1];
                f32x4 p2 = xv0 * wf0[2] + xv1 * wf1[2];
                f32x4 p3 = xv0 * wf0[3] + xv1 * wf1[3];
                d0 = p0[0] + p0[1] + p0[2] + p0[3];
                d1 = p1[0] + p1[1] + p1[2] + p1[3];
                d2 = p2[0] + p2[1] + p2[2] + p2[3];
                d3 = p3[0] + p3[1] + p3[2] + p3[3];
            }
            float gi = acc[m][0][q] + bq[0] + d0;
            float gf = acc[m][1][q] + bq[1] + d1;
            float gg = acc[m][2][q] + bq[2] + d2;
            float go = acc[m][3][q] + bq[3] + d3;
            float iv = sigf(gi), fv = sigf(gf), gv = tanhf_(gg), ov = sigf(go);
            size_t ci = (size_t)r * HID + hu;
            float cn = fv * cst[ci] + iv * gv;
            cst[ci] = cn;
            hdst[ci] = (bf16)(ov * tanhf_(cn));
        }
    }
}

// ---------------------------------------------------------------------------
// Standalone LSTM cell (decoder + encoder-final). grid (32,16).
// ---------------------------------------------------------------------------
template<int NPASS, bool HASX>
__global__ __launch_bounds__(256)
void lstm_step(const bf16* __restrict__ A1, const bf16* __restrict__ W1,
               const bf16* __restrict__ A2, const bf16* __restrict__ W2,
               const float* __restrict__ Wfc, const float* __restrict__ bias,
               const float* __restrict__ xA, int sx,
               float* __restrict__ cst, bf16* __restrict__ hdst)
{
    __shared__ __align__(16) bf16 As[2][4096], Ws[2][4096];
    int bx, by; swz32(bx, by);
    const int m0 = bx * 128, n0 = by * 128;
    f32x4 acc[4][4];
#pragma unroll
    for (int m = 0; m < 4; ++m)
#pragma unroll
        for (int n = 0; n < 4; ++n) acc[m][n] = (f32x4){0.f, 0.f, 0.f, 0.f};
    gemm_acc(A1, W1, A2, W2, NPASS, m0, n0, As, Ws, acc);
    lstm_epi<HASX>(acc, Wfc, bias, xA, sx, cst, hdst, m0, n0);
}

// ---------------------------------------------------------------------------
// Fused encoder step: layer0[t+1] (by<16) || layer1[t] (by>=16). grid (32,32).
// ---------------------------------------------------------------------------
template<bool L1TWO>
__global__ __launch_bounds__(256)
void enc_fused(const bf16* __restrict__ h0_in, const bf16* __restrict__ Whh0c,
               const float* __restrict__ Wf0c, const float* __restrict__ bf0c,
               const float* __restrict__ xA,
               bf16* __restrict__ h0_out, float* __restrict__ c0,
               const bf16* __restrict__ Wih1c, const bf16* __restrict__ h1_in,
               const bf16* __restrict__ Whh1c, const float* __restrict__ bs1c,
               bf16* __restrict__ h1_out, float* __restrict__ c1)
{
    __shared__ __align__(16) bf16 As[2][4096], Ws[2][4096];
    int bx, by; swz32(bx, by);
    const int m0 = bx * 128;
    f32x4 acc[4][4];
#pragma unroll
    for (int m = 0; m < 4; ++m)
#pragma unroll
        for (int n = 0; n < 4; ++n) acc[m][n] = (f32x4){0.f, 0.f, 0.f, 0.f};
    if (by < 16) {
        const int n0 = by * 128;
        gemm_acc(h0_in, Whh0c, nullptr, nullptr, 1, m0, n0, As, Ws, acc);
        lstm_epi<true>(acc, Wf0c, bf0c, xA, TSTEPS * FINP, c0, h0_out, m0, n0);
    } else {
        const int n0 = (by - 16) * 128;
        gemm_acc(h0_in, Wih1c, h1_in, Whh1c, L1TWO ? 2 : 1, m0, n0, As, Ws, acc);
        lstm_epi<false>(acc, nullptr, bs1c, nullptr, 0, c1, h1_out, m0, n0);
    }
}

// ---------------------------------------------------------------------------
// Encoder step 0 (h=0, c=0): epilogue-only. grid 8192 x 256.
// ---------------------------------------------------------------------------
__global__ __launch_bounds__(256)
void init_step(const float* __restrict__ x, const float* __restrict__ Wf0c,
               const float* __restrict__ bf0c, bf16* __restrict__ h0,
               float* __restrict__ c0)
{
    int idx = blockIdx.x * 256 + threadIdx.x;     // = r*512 + hu
    int r = idx >> 9, hu = idx & 511;
    const float* xr = x + (size_t)r * (TSTEPS * FINP);
    f32x4 xv0 = *(const f32x4*)xr;
    f32x4 xv1 = *(const f32x4*)(xr + 4);
    int jb = ((hu >> 4) << 6) + (hu & 15);
    float g[4];
#pragma unroll
    for (int gg = 0; gg < 4; ++gg) {
        const float* wrow = Wf0c + (size_t)(jb + gg * 16) * 8;
        f32x4 w0 = *(const f32x4*)wrow;
        f32x4 w1 = *(const f32x4*)(wrow + 4);
        f32x4 p = xv0 * w0 + xv1 * w1;
        g[gg] = bf0c[jb + gg * 16] + p[0] + p[1] + p[2] + p[3];
    }
    float iv = sigf(g[0]), gv = tanhf_(g[2]), ov = sigf(g[3]);
    float cn = iv * gv;                            // c_prev = 0
    c0[idx] = cn;
    h0[idx] = (bf16)(ov * tanhf_(cn));
}

// ---------------------------------------------------------------------------
// fc1: Z = A @ W^T + b (fp32 out). grid (32,4).
// ---------------------------------------------------------------------------
__global__ __launch_bounds__(256)
void fc1_mfma(const bf16* __restrict__ A, const bf16* __restrict__ W,
              const float* __restrict__ bias, float* __restrict__ Z)
{
    __shared__ __align__(16) bf16 As[2][4096], Ws[2][4096];
    int bx, by; swz32(bx, by);
    const int m0 = bx * 128, n0 = by * 128;
    f32x4 acc[4][4];
#pragma unroll
    for (int m = 0; m < 4; ++m)
#pragma unroll
        for (int n = 0; n < 4; ++n) acc[m][n] = (f32x4){0.f, 0.f, 0.f, 0.f};
    gemm_acc(A, W, nullptr, nullptr, 1, m0, n0, As, Ws, acc);

    const int tid = threadIdx.x, lane = tid & 63, w = tid >> 6;
    const int wr = w >> 1, wc = w & 1, l16 = lane & 15, lq = lane >> 4;
#pragma unroll
    for (int m = 0; m < 4; ++m) {
        const int rb = m0 + wr * 64 + m * 16 + lq * 4;
#pragma unroll
        for (int n = 0; n < 4; ++n) {
            const int col = n0 + wc * 64 + n * 16 + l16;
            float bv = bias[col];
#pragma unroll
            for (int q = 0; q < 4; ++q)
                Z[(size_t)(rb + q) * HID + col] = acc[m][n][q] + bv;
        }
    }
}

// ---------------------------------------------------------------------------
// LayerNorm + ReLU + fc2 (8 outs), one wave per row.
// ---------------------------------------------------------------------------
__global__ __launch_bounds__(256)
void ln_fc2_kernel(const float* __restrict__ Z, const float* __restrict__ lng,
                   const float* __restrict__ lnb, const float* __restrict__ w2,
                   const float* __restrict__ b2, float* __restrict__ out)
{
    int wave = threadIdx.x >> 6;
    int lane = threadIdx.x & 63;
    int n = blockIdx.x * 4 + wave;
    const float* zr = Z + (size_t)n * HID;

    float v[8];
    float s1 = 0.f, s2 = 0.f;
#pragma unroll
    for (int j = 0; j < 8; ++j) {
        v[j] = zr[lane + j * 64];
        s1 += v[j];
        s2 += v[j] * v[j];
    }
#pragma unroll
    for (int off = 32; off; off >>= 1) {
        s1 += __shfl_down(s1, off);
        s2 += __shfl_down(s2, off);
    }
    s1 = __shfl(s1, 0);
    s2 = __shfl(s2, 0);
    float mu = s1 * (1.f / 512.f);
    float var = s2 * (1.f / 512.f) - mu * mu;
    float rs = rsqrtf(var + 1e-5f);

    float y[8];
#pragma unroll
    for (int f = 0; f < 8; ++f) y[f] = 0.f;
#pragma unroll
    for (int j = 0; j < 8; ++j) {
        int h = lane + j * 64;
        float zn = (v[j] - mu) * rs * lng[h] + lnb[h];
        zn = fmaxf(zn, 0.f);
#pragma unroll
        for (int f = 0; f < 8; ++f) y[f] += zn * w2[f * HID + h];
    }
#pragma unroll
    for (int f = 0; f < 8; ++f)
#pragma unroll
        for (int off = 32; off; off >>= 1) y[f] += __shfl_down(y[f], off);

    if (lane == 0) {
#pragma unroll
        for (int f = 0; f < 8; ++f) out[(size_t)n * 256 + f] = y[f] + b2[f];
    }
}

// ---------------------------------------------------------------------------
// Weight preprocessing
// ---------------------------------------------------------------------------
__device__ __forceinline__ int remap_j(int j) {
    int gate = j >> 9, hu = j & 511;
    return ((hu >> 4) << 6) + (gate << 4) + (hu & 15);
}

__global__ void fold_small(const float* __restrict__ Wih0, const float* __restrict__ We,
                           const float* __restrict__ be, const float* __restrict__ bih0,
                           const float* __restrict__ bhh0, const float* __restrict__ bih1,
                           const float* __restrict__ bhh1,
                           float* __restrict__ Wf0c, float* __restrict__ bf0c,
                           float* __restrict__ bs1c)
{
    int j = blockIdx.x * 256 + threadIdx.x;
    if (j >= G4H) return;
    int jn = remap_j(j);
    float acc[FINP];
#pragma unroll
    for (int f = 0; f < FINP; ++f) acc[f] = 0.f;
    float bacc = 0.f;
    for (int e = 0; e < EDIM; ++e) {
        float wv = Wih0[(size_t)j * EDIM + e];
        bacc += wv * be[e];
#pragma unroll
        for (int f = 0; f < FINP; ++f) acc[f] += wv * We[e * FINP + f];
    }
#pragma unroll
    for (int f = 0; f < FINP; ++f) Wf0c[(size_t)jn * FINP + f] = acc[f];
    bf0c[jn] = bacc + bih0[j] + bhh0[j];
    bs1c[jn] = bih1[j] + bhh1[j];
}

__global__ void conv_w(const float* __restrict__ W0, const float* __restrict__ W1,
                       const float* __restrict__ W2,
                       bf16* __restrict__ O0, bf16* __restrict__ O1, bf16* __restrict__ O2)
{
    int j = blockIdx.x;
    int which = blockIdx.y;
    const float* src = which == 0 ? W0 : which == 1 ? W1 : W2;
    bf16* dst = which == 0 ? O0 : which == 1 ? O1 : O2;
    int jn = remap_j(j);
    for (int k = threadIdx.x; k < HID; k += 256)
        dst[(size_t)jn * HID + k] = (bf16)src[(size_t)j * HID + k];
}

__global__ void conv_fc1(const float* __restrict__ W, bf16* __restrict__ O)
{
    int j = blockIdx.x;
    for (int k = threadIdx.x; k < HID; k += 256)
        O[(size_t)j * HID + k] = (bf16)W[(size_t)j * HID + k];
}

// ---------------------------------------------------------------------------
extern "C" void kernel_launch(void* const* d_in, const int* in_sizes, int n_in,
                              void* d_out, int out_size, void* d_ws, size_t ws_size,
                              hipStream_t stream)
{
    const float* x    = (const float*)d_in[0];
    const float* We   = (const float*)d_in[1];
    const float* be   = (const float*)d_in[2];
    const float* Wih0 = (const float*)d_in[3];
    const float* Whh0 = (const float*)d_in[4];
    const float* bih0 = (const float*)d_in[5];
    const float* bhh0 = (const float*)d_in[6];
    const float* Wih1 = (const float*)d_in[7];
    const float* Whh1 = (const float*)d_in[8];
    const float* bih1 = (const float*)d_in[9];
    const float* bhh1 = (const float*)d_in[10];
    const float* fc1w = (const float*)d_in[11];
    const float* fc1b = (const float*)d_in[12];
    const float* lng  = (const float*)d_in[13];
    const float* lnb  = (const float*)d_in[14];
    const float* fc2w = (const float*)d_in[15];
    const float* fc2b = (const float*)d_in[16];
    float* out = (float*)d_out;

    char* p = (char*)d_ws;
    auto alloc = [&](size_t bytes) -> void* {
        void* r = (void*)p;
        p += (bytes + 255) & ~(size_t)255;
        return r;
    };
    bf16*  Whh0c = (bf16*)alloc((size_t)G4H * HID * 2);
    bf16*  Wih1c = (bf16*)alloc((size_t)G4H * HID * 2);
    bf16*  Whh1c = (bf16*)alloc((size_t)G4H * HID * 2);
    bf16*  fc1wb = (bf16*)alloc((size_t)HID * HID * 2);
    float* Wf0c  = (float*)alloc((size_t)G4H * FINP * 4);
    float* bf0c  = (float*)alloc((size_t)G4H * 4);
    float* bs1c  = (float*)alloc((size_t)G4H * 4);
    const size_t S = (size_t)NB * HID;
    bf16*  H0[2]; H0[0] = (bf16*)alloc(S * 2); H0[1] = (bf16*)alloc(S * 2);
    bf16*  H1[2]; H1[0] = (bf16*)alloc(S * 2); H1[1] = (bf16*)alloc(S * 2);
    float* c0    = (float*)alloc(S * 4);
    float* c1    = (float*)alloc(S * 4);
    float* Z     = (float*)alloc(S * 4);

    hipMemsetAsync(c1, 0, S * 4, stream);   // layer1[0] epilogue reads c1

    fold_small<<<8, 256, 0, stream>>>(Wih0, We, be, bih0, bhh0, bih1, bhh1, Wf0c, bf0c, bs1c);
    conv_w<<<dim3(G4H, 3), 256, 0, stream>>>(Whh0, Wih1, Whh1, Whh0c, Wih1c, Whh1c);
    conv_fc1<<<HID, 256, 0, stream>>>(fc1w, fc1wb);

    // ----- encoder: t = 0..62 (63 steps). h0[t] in H0[t&1], h1[t] in H1[t&1].
    init_step<<<NB * HID / 256, 256, 0, stream>>>(x, Wf0c, bf0c, H0[0], c0);

    dim3 fg(32, 32), lb(256);
    for (int t = 0; t < TSTEPS - 2; ++t) {   // t = 0..61: layer0[t+1] || layer1[t]
        if (t == 0)
            enc_fused<false><<<fg, lb, 0, stream>>>(H0[0], Whh0c, Wf0c, bf0c,
                x + (size_t)1 * FINP, H0[1], c0,
                Wih1c, nullptr, Whh1c, bs1c, H1[0], c1);
        else
            enc_fused<true><<<fg, lb, 0, stream>>>(H0[t & 1], Whh0c, Wf0c, bf0c,
                x + (size_t)(t + 1) * FINP, H0[(t + 1) & 1], c0,
                Wih1c, H1[(t + 1) & 1], Whh1c, bs1c, H1[t & 1], c1);
    }
    // final layer1[62]: reads h0[62]=H0[0], h1[61]=H1[1], writes H1[0]
    lstm_step<2, false><<<dim3(32, 16), lb, 0, stream>>>(
        H0[0], Wih1c, H1[1], Whh1c, nullptr, bs1c, nullptr, 0, c1, H1[0]);

    // ----- decoder: s = 0..31.
    for (int s = 0; s < FWIN; ++s) {
        const float* xA = (s == 0) ? (x + (size_t)(TSTEPS - 1) * FINP)
                                   : (out + (size_t)(s - 1) * FINP);
        int sx = (s == 0) ? (TSTEPS * FINP) : (FWIN * FINP);
        lstm_step<1, true><<<dim3(32, 16), lb, 0, stream>>>(
            H0[s & 1], Whh0c, nullptr, nullptr, Wf0c, bf0c, xA, sx, c0, H0[(s + 1) & 1]);
        lstm_step<2, false><<<dim3(32, 16), lb, 0, stream>>>(
            H0[(s + 1) & 1], Wih1c, H1[s & 1], Whh1c, nullptr, bs1c, nullptr, 0,
            c1, H1[(s + 1) & 1]);
        fc1_mfma<<<dim3(32, 4), lb, 0, stream>>>(H1[(s + 1) & 1], fc1wb, fc1b, Z);
        ln_fc2_kernel<<<NB / 4, 256, 0, stream>>>(Z, lng, lnb, fc2w, fc2b,
                                                  out + (size_t)s * FINP);
    }
}

// Round 7
// 8141.319 us; speedup vs baseline: 1.0260x; 1.0260x over previous
//
#include <hip/hip_runtime.h>
#include <math.h>

#define NB   4096
#define HID  512
#define G4H  2048
#define EDIM 256
#define FINP 8
#define TSTEPS 64
#define FWIN 32

typedef __bf16 bf16;
typedef bf16  bf16x8 __attribute__((ext_vector_type(8)));
typedef float f32x4  __attribute__((ext_vector_type(4)));

__device__ __forceinline__ float sigf(float x) { return 1.0f / (1.0f + __expf(-x)); }
__device__ __forceinline__ float tanhf_(float x) { return 2.0f * sigf(2.0f * x) - 1.0f; }

__device__ __forceinline__ void gload16(const void* g, void* l) {
    __builtin_amdgcn_global_load_lds((const __attribute__((address_space(1))) void*)g,
                                     (__attribute__((address_space(3))) void*)l, 16, 0, 0);
}

// Bijective XCD-chunked swizzle (nwg % 8 == 0; gridDim.x == 32)
__device__ __forceinline__ void swz32(int& bx, int& by) {
    int nwg  = (int)(gridDim.x * gridDim.y);
    int orig = (int)(blockIdx.x + blockIdx.y * gridDim.x);
    int swz  = (orig & 7) * (nwg >> 3) + (orig >> 3);
    bx = swz & 31;
    by = swz >> 5;
}

// ---------------------------------------------------------------------------
// 128x128-tile bf16 MFMA accumulate over npass*512 K.
// LDS layout (per 8KB buffer): 512 chunks of 16B, chunk c holds
//   A[row=(c>>6)*16+(c&15)][8 bf16 at koct=(c>>4)&3] -- fragment-major: a
//   wave's frag read is base + lane*16 (contiguous 1KB, conflict-free; R6
//   measured SQ_LDS_BANK_CONFLICT==0) and gload_lds dst stays linear.
// Loop: 1 __syncthreads per iter (R3 form -- compiler-managed waitcnts;
//   R6's counted-vmcnt 2-barrier variant measured SLOWER, reverted).
// 256 threads = 4 waves (2x2 of 64x64). A,W row-major ld=512.
// ---------------------------------------------------------------------------
__device__ __forceinline__ void gemm_acc(
    const bf16* __restrict__ A1, const bf16* __restrict__ W1,
    const bf16* __restrict__ A2, const bf16* __restrict__ W2, int npass,
    int m0, int n0, bf16 (&As)[2][4096], bf16 (&Ws)[2][4096], f32x4 (&acc)[4][4])
{
    const int tid  = threadIdx.x;
    const int lane = tid & 63;
    const int w    = tid >> 6;
    const int wr   = w >> 1, wc = w & 1;
    const int NK   = npass << 4;

    // staging: thread covers chunks tid and tid+256 (fragment-major source perm)
    const int r0 = ((tid >> 6) << 4) + (tid & 15);
    const int o0 = ((tid >> 4) & 3) * 8;
    const int t1 = tid + 256;
    const int r1 = ((t1 >> 6) << 4) + (t1 & 15);
    const int o1 = ((t1 >> 4) & 3) * 8;

    auto stage = [&](int s, int b) {
        const bf16* A = (s < 16) ? A1 : A2;
        const bf16* W = (s < 16) ? W1 : W2;
        const int k0 = (s & 15) << 5;
        gload16(A + (size_t)(m0 + r0) * HID + k0 + o0, &As[b][tid * 8]);
        gload16(A + (size_t)(m0 + r1) * HID + k0 + o1, &As[b][(tid + 256) * 8]);
        gload16(W + (size_t)(n0 + r0) * HID + k0 + o0, &Ws[b][tid * 8]);
        gload16(W + (size_t)(n0 + r1) * HID + k0 + o1, &Ws[b][(tid + 256) * 8]);
    };

    stage(0, 0);
    __syncthreads();                              // buf0 ready (vmcnt drained)
    int cur = 0;
    for (int s = 0; s < NK; ++s) {
        if (s + 1 < NK) stage(s + 1, cur ^ 1);    // prefetch overlaps compute
        const bf16* abase = &As[cur][(wr << 2) * 512 + lane * 8];
        const bf16* bbase = &Ws[cur][(wc << 2) * 512 + lane * 8];
        bf16x8 af[4], bfr[4];
#pragma unroll
        for (int m = 0; m < 4; ++m) af[m] = *(const bf16x8*)(abase + m * 512);
#pragma unroll
        for (int n = 0; n < 4; ++n) bfr[n] = *(const bf16x8*)(bbase + n * 512);
#pragma unroll
        for (int m = 0; m < 4; ++m)
#pragma unroll
            for (int n = 0; n < 4; ++n)
                acc[m][n] = __builtin_amdgcn_mfma_f32_16x16x32_bf16(af[m], bfr[n], acc[m][n], 0, 0, 0);
        __syncthreads();                          // drain prefetch + all reads done
        cur ^= 1;
    }
}

// ---------------------------------------------------------------------------
// LSTM epilogue. Weight rows pre-reordered: j_new = (hu>>4)*64 + gate*16 +
// (hu&15) -> wave's 4 N-frags are gates i,f,g,o of 16 hus (lane-local).
// ---------------------------------------------------------------------------
template<bool HASX>
__device__ __forceinline__ void lstm_epi(f32x4 (&acc)[4][4],
    const float* __restrict__ Wfc, const float* __restrict__ bias,
    const float* __restrict__ xA, int sx,
    float* __restrict__ cst, bf16* __restrict__ hdst, int m0, int n0)
{
    const int tid = threadIdx.x, lane = tid & 63, w = tid >> 6;
    const int wr = w >> 1, wc = w & 1, l16 = lane & 15, lq = lane >> 4;
    const int hu = (n0 >> 2) + wc * 16 + l16;
    const int jb = n0 + wc * 64 + l16;

    float bq[4];
    f32x4 wf0[4], wf1[4];
#pragma unroll
    for (int g = 0; g < 4; ++g) {
        bq[g] = bias[jb + g * 16];
        if constexpr (HASX) {
            const float* wrow = Wfc + (size_t)(jb + g * 16) * 8;
            wf0[g] = *(const f32x4*)wrow;
            wf1[g] = *(const f32x4*)(wrow + 4);
        }
    }
#pragma unroll
    for (int m = 0; m < 4; ++m) {
        const int rb = m0 + wr * 64 + m * 16 + lq * 4;
#pragma unroll
        for (int q = 0; q < 4; ++q) {
            const int r = rb + q;
            float d0 = 0.f, d1 = 0.f, d2 = 0.f, d3 = 0.f;
            if constexpr (HASX) {
                const float* xr = xA + (size_t)r * sx;
                f32x4 xv0 = *(const f32x4*)xr;
                f32x4 xv1 = *(const f32x4*)(xr + 4);
                f32x4 p0 = xv0 * wf0[0] + xv1 * wf1[0];
                f32x4 p1 = xv0 * wf0[1] + xv1 * wf1[1];
                f32x4 p2 = xv0 * wf0[2] + xv1 * wf1[2];
                f32x4 p3 = xv0 * wf0[3] + xv1 * wf1[3];
                d0 = p0[0] + p0[1] + p0[2] + p0[3];
                d1 = p1[0] + p1[1] + p1[2] + p1[3];
                d2 = p2[0] + p2[1] + p2[2] + p2[3];
                d3 = p3[0] + p3[1] + p3[2] + p3[3];
            }
            float gi = acc[m][0][q] + bq[0] + d0;
            float gf = acc[m][1][q] + bq[1] + d1;
            float gg = acc[m][2][q] + bq[2] + d2;
            float go = acc[m][3][q] + bq[3] + d3;
            float iv = sigf(gi), fv = sigf(gf), gv = tanhf_(gg), ov = sigf(go);
            size_t ci = (size_t)r * HID + hu;
            float cn = fv * cst[ci] + iv * gv;
            cst[ci] = cn;
            hdst[ci] = (bf16)(ov * tanhf_(cn));
        }
    }
}

// ---------------------------------------------------------------------------
// Standalone LSTM cell (decoder + encoder-final). grid (32,16).
// ---------------------------------------------------------------------------
template<int NPASS, bool HASX>
__global__ __launch_bounds__(256)
void lstm_step(const bf16* __restrict__ A1, const bf16* __restrict__ W1,
               const bf16* __restrict__ A2, const bf16* __restrict__ W2,
               const float* __restrict__ Wfc, const float* __restrict__ bias,
               const float* __restrict__ xA, int sx,
               float* __restrict__ cst, bf16* __restrict__ hdst)
{
    __shared__ __align__(16) bf16 As[2][4096], Ws[2][4096];
    int bx, by; swz32(bx, by);
    const int m0 = bx * 128, n0 = by * 128;
    f32x4 acc[4][4];
#pragma unroll
    for (int m = 0; m < 4; ++m)
#pragma unroll
        for (int n = 0; n < 4; ++n) acc[m][n] = (f32x4){0.f, 0.f, 0.f, 0.f};
    gemm_acc(A1, W1, A2, W2, NPASS, m0, n0, As, Ws, acc);
    lstm_epi<HASX>(acc, Wfc, bias, xA, sx, cst, hdst, m0, n0);
}

// ---------------------------------------------------------------------------
// Fused encoder step: layer0[t+1] || layer1[t], grid (32,32).
// BALANCED mapping: layer = swz&1 (alternating), so each XCD-chunk of 128
// consecutive swz indices holds 64 short (1-pass) + 64 long (2-pass) blocks
// -> every XCD/CU gets a 50/50 mix (R3/R6's by<16 split concentrated all
// short blocks on XCDs 0-3 -> half-machine idle tail; fixed here).
// ---------------------------------------------------------------------------
template<bool L1TWO>
__global__ __launch_bounds__(256)
void enc_fused(const bf16* __restrict__ h0_in, const bf16* __restrict__ Whh0c,
               const float* __restrict__ Wf0c, const float* __restrict__ bf0c,
               const float* __restrict__ xA,
               bf16* __restrict__ h0_out, float* __restrict__ c0,
               const bf16* __restrict__ Wih1c, const bf16* __restrict__ h1_in,
               const bf16* __restrict__ Whh1c, const float* __restrict__ bs1c,
               bf16* __restrict__ h1_out, float* __restrict__ c1)
{
    __shared__ __align__(16) bf16 As[2][4096], Ws[2][4096];
    int orig = (int)(blockIdx.x + blockIdx.y * gridDim.x);    // 0..1023
    int swz  = (orig & 7) * 128 + (orig >> 3);                // XCD-chunked
    int layer = swz & 1;
    int rest  = swz >> 1;                                     // 0..511
    const int m0 = (rest & 31) * 128;
    const int n0 = (rest >> 5) * 128;
    f32x4 acc[4][4];
#pragma unroll
    for (int m = 0; m < 4; ++m)
#pragma unroll
        for (int n = 0; n < 4; ++n) acc[m][n] = (f32x4){0.f, 0.f, 0.f, 0.f};
    if (layer == 0) {
        gemm_acc(h0_in, Whh0c, nullptr, nullptr, 1, m0, n0, As, Ws, acc);
        lstm_epi<true>(acc, Wf0c, bf0c, xA, TSTEPS * FINP, c0, h0_out, m0, n0);
    } else {
        gemm_acc(h0_in, Wih1c, h1_in, Whh1c, L1TWO ? 2 : 1, m0, n0, As, Ws, acc);
        lstm_epi<false>(acc, nullptr, bs1c, nullptr, 0, c1, h1_out, m0, n0);
    }
}

// ---------------------------------------------------------------------------
// Encoder step 0 (h=0, c=0): epilogue-only. grid 8192 x 256.
// ---------------------------------------------------------------------------
__global__ __launch_bounds__(256)
void init_step(const float* __restrict__ x, const float* __restrict__ Wf0c,
               const float* __restrict__ bf0c, bf16* __restrict__ h0,
               float* __restrict__ c0)
{
    int idx = blockIdx.x * 256 + threadIdx.x;     // = r*512 + hu
    int r = idx >> 9, hu = idx & 511;
    const float* xr = x + (size_t)r * (TSTEPS * FINP);
    f32x4 xv0 = *(const f32x4*)xr;
    f32x4 xv1 = *(const f32x4*)(xr + 4);
    int jb = ((hu >> 4) << 6) + (hu & 15);
    float g[4];
#pragma unroll
    for (int gg = 0; gg < 4; ++gg) {
        const float* wrow = Wf0c + (size_t)(jb + gg * 16) * 8;
        f32x4 w0 = *(const f32x4*)wrow;
        f32x4 w1 = *(const f32x4*)(wrow + 4);
        f32x4 p = xv0 * w0 + xv1 * w1;
        g[gg] = bf0c[jb + gg * 16] + p[0] + p[1] + p[2] + p[3];
    }
    float iv = sigf(g[0]), gv = tanhf_(g[2]), ov = sigf(g[3]);
    float cn = iv * gv;                            // c_prev = 0
    c0[idx] = cn;
    h0[idx] = (bf16)(ov * tanhf_(cn));
}

// ---------------------------------------------------------------------------
// fc1: Z = A @ W^T + b (fp32 out). grid (32,4).
// ---------------------------------------------------------------------------
__global__ __launch_bounds__(256)
void fc1_mfma(const bf16* __restrict__ A, const bf16* __restrict__ W,
              const float* __restrict__ bias, float* __restrict__ Z)
{
    __shared__ __align__(16) bf16 As[2][4096], Ws[2][4096];
    int bx, by; swz32(bx, by);
    const int m0 = bx * 128, n0 = by * 128;
    f32x4 acc[4][4];
#pragma unroll
    for (int m = 0; m < 4; ++m)
#pragma unroll
        for (int n = 0; n < 4; ++n) acc[m][n] = (f32x4){0.f, 0.f, 0.f, 0.f};
    gemm_acc(A, W, nullptr, nullptr, 1, m0, n0, As, Ws, acc);

    const int tid = threadIdx.x, lane = tid & 63, w = tid >> 6;
    const int wr = w >> 1, wc = w & 1, l16 = lane & 15, lq = lane >> 4;
#pragma unroll
    for (int m = 0; m < 4; ++m) {
        const int rb = m0 + wr * 64 + m * 16 + lq * 4;
#pragma unroll
        for (int n = 0; n < 4; ++n) {
            const int col = n0 + wc * 64 + n * 16 + l16;
            float bv = bias[col];
#pragma unroll
            for (int q = 0; q < 4; ++q)
                Z[(size_t)(rb + q) * HID + col] = acc[m][n][q] + bv;
        }
    }
}

// ---------------------------------------------------------------------------
// LayerNorm + ReLU + fc2 (8 outs), one wave per row.
// ---------------------------------------------------------------------------
__global__ __launch_bounds__(256)
void ln_fc2_kernel(const float* __restrict__ Z, const float* __restrict__ lng,
                   const float* __restrict__ lnb, const float* __restrict__ w2,
                   const float* __restrict__ b2, float* __restrict__ out)
{
    int wave = threadIdx.x >> 6;
    int lane = threadIdx.x & 63;
    int n = blockIdx.x * 4 + wave;
    const float* zr = Z + (size_t)n * HID;

    float v[8];
    float s1 = 0.f, s2 = 0.f;
#pragma unroll
    for (int j = 0; j < 8; ++j) {
        v[j] = zr[lane + j * 64];
        s1 += v[j];
        s2 += v[j] * v[j];
    }
#pragma unroll
    for (int off = 32; off; off >>= 1) {
        s1 += __shfl_down(s1, off);
        s2 += __shfl_down(s2, off);
    }
    s1 = __shfl(s1, 0);
    s2 = __shfl(s2, 0);
    float mu = s1 * (1.f / 512.f);
    float var = s2 * (1.f / 512.f) - mu * mu;
    float rs = rsqrtf(var + 1e-5f);

    float y[8];
#pragma unroll
    for (int f = 0; f < 8; ++f) y[f] = 0.f;
#pragma unroll
    for (int j = 0; j < 8; ++j) {
        int h = lane + j * 64;
        float zn = (v[j] - mu) * rs * lng[h] + lnb[h];
        zn = fmaxf(zn, 0.f);
#pragma unroll
        for (int f = 0; f < 8; ++f) y[f] += zn * w2[f * HID + h];
    }
#pragma unroll
    for (int f = 0; f < 8; ++f)
#pragma unroll
        for (int off = 32; off; off >>= 1) y[f] += __shfl_down(y[f], off);

    if (lane == 0) {
#pragma unroll
        for (int f = 0; f < 8; ++f) out[(size_t)n * 256 + f] = y[f] + b2[f];
    }
}

// ---------------------------------------------------------------------------
// Weight preprocessing
// ---------------------------------------------------------------------------
__device__ __forceinline__ int remap_j(int j) {
    int gate = j >> 9, hu = j & 511;
    return ((hu >> 4) << 6) + (gate << 4) + (hu & 15);
}

__global__ void fold_small(const float* __restrict__ Wih0, const float* __restrict__ We,
                           const float* __restrict__ be, const float* __restrict__ bih0,
                           const float* __restrict__ bhh0, const float* __restrict__ bih1,
                           const float* __restrict__ bhh1,
                           float* __restrict__ Wf0c, float* __restrict__ bf0c,
                           float* __restrict__ bs1c)
{
    int j = blockIdx.x * 256 + threadIdx.x;
    if (j >= G4H) return;
    int jn = remap_j(j);
    float acc[FINP];
#pragma unroll
    for (int f = 0; f < FINP; ++f) acc[f] = 0.f;
    float bacc = 0.f;
    for (int e = 0; e < EDIM; ++e) {
        float wv = Wih0[(size_t)j * EDIM + e];
        bacc += wv * be[e];
#pragma unroll
        for (int f = 0; f < FINP; ++f) acc[f] += wv * We[e * FINP + f];
    }
#pragma unroll
    for (int f = 0; f < FINP; ++f) Wf0c[(size_t)jn * FINP + f] = acc[f];
    bf0c[jn] = bacc + bih0[j] + bhh0[j];
    bs1c[jn] = bih1[j] + bhh1[j];
}

__global__ void conv_w(const float* __restrict__ W0, const float* __restrict__ W1,
                       const float* __restrict__ W2,
                       bf16* __restrict__ O0, bf16* __restrict__ O1, bf16* __restrict__ O2)
{
    int j = blockIdx.x;
    int which = blockIdx.y;
    const float* src = which == 0 ? W0 : which == 1 ? W1 : W2;
    bf16* dst = which == 0 ? O0 : which == 1 ? O1 : O2;
    int jn = remap_j(j);
    for (int k = threadIdx.x; k < HID; k += 256)
        dst[(size_t)jn * HID + k] = (bf16)src[(size_t)j * HID + k];
}

__global__ void conv_fc1(const float* __restrict__ W, bf16* __restrict__ O)
{
    int j = blockIdx.x;
    for (int k = threadIdx.x; k < HID; k += 256)
        O[(size_t)j * HID + k] = (bf16)W[(size_t)j * HID + k];
}

// ---------------------------------------------------------------------------
extern "C" void kernel_launch(void* const* d_in, const int* in_sizes, int n_in,
                              void* d_out, int out_size, void* d_ws, size_t ws_size,
                              hipStream_t stream)
{
    const float* x    = (const float*)d_in[0];
    const float* We   = (const float*)d_in[1];
    const float* be   = (const float*)d_in[2];
    const float* Wih0 = (const float*)d_in[3];
    const float* Whh0 = (const float*)d_in[4];
    const float* bih0 = (const float*)d_in[5];
    const float* bhh0 = (const float*)d_in[6];
    const float* Wih1 = (const float*)d_in[7];
    const float* Whh1 = (const float*)d_in[8];
    const float* bih1 = (const float*)d_in[9];
    const float* bhh1 = (const float*)d_in[10];
    const float* fc1w = (const float*)d_in[11];
    const float* fc1b = (const float*)d_in[12];
    const float* lng  = (const float*)d_in[13];
    const float* lnb  = (const float*)d_in[14];
    const float* fc2w = (const float*)d_in[15];
    const float* fc2b = (const float*)d_in[16];
    float* out = (float*)d_out;

    char* p = (char*)d_ws;
    auto alloc = [&](size_t bytes) -> void* {
        void* r = (void*)p;
        p += (bytes + 255) & ~(size_t)255;
        return r;
    };
    bf16*  Whh0c = (bf16*)alloc((size_t)G4H * HID * 2);
    bf16*  Wih1c = (bf16*)alloc((size_t)G4H * HID * 2);
    bf16*  Whh1c = (bf16*)alloc((size_t)G4H * HID * 2);
    bf16*  fc1wb = (bf16*)alloc((size_t)HID * HID * 2);
    float* Wf0c  = (float*)alloc((size_t)G4H * FINP * 4);
    float* bf0c  = (float*)alloc((size_t)G4H * 4);
    float* bs1c  = (float*)alloc((size_t)G4H * 4);
    const size_t S = (size_t)NB * HID;
    bf16*  H0[2]; H0[0] = (bf16*)alloc(S * 2); H0[1] = (bf16*)alloc(S * 2);
    bf16*  H1[2]; H1[0] = (bf16*)alloc(S * 2); H1[1] = (bf16*)alloc(S * 2);
    float* c0    = (float*)alloc(S * 4);
    float* c1    = (float*)alloc(S * 4);
    float* Z     = (float*)alloc(S * 4);

    hipMemsetAsync(c1, 0, S * 4, stream);   // layer1[0] epilogue reads c1

    fold_small<<<8, 256, 0, stream>>>(Wih0, We, be, bih0, bhh0, bih1, bhh1, Wf0c, bf0c, bs1c);
    conv_w<<<dim3(G4H, 3), 256, 0, stream>>>(Whh0, Wih1, Whh1, Whh0c, Wih1c, Whh1c);
    conv_fc1<<<HID, 256, 0, stream>>>(fc1w, fc1wb);

    // ----- encoder: t = 0..62 (63 steps). h0[t] in H0[t&1], h1[t] in H1[t&1].
    init_step<<<NB * HID / 256, 256, 0, stream>>>(x, Wf0c, bf0c, H0[0], c0);

    dim3 fg(32, 32), lb(256);
    for (int t = 0; t < TSTEPS - 2; ++t) {   // t = 0..61: layer0[t+1] || layer1[t]
        if (t == 0)
            enc_fused<false><<<fg, lb, 0, stream>>>(H0[0], Whh0c, Wf0c, bf0c,
                x + (size_t)1 * FINP, H0[1], c0,
                Wih1c, nullptr, Whh1c, bs1c, H1[0], c1);
        else
            enc_fused<true><<<fg, lb, 0, stream>>>(H0[t & 1], Whh0c, Wf0c, bf0c,
                x + (size_t)(t + 1) * FINP, H0[(t + 1) & 1], c0,
                Wih1c, H1[(t + 1) & 1], Whh1c, bs1c, H1[t & 1], c1);
    }
    // final layer1[62]: reads h0[62]=H0[0], h1[61]=H1[1], writes H1[0]
    lstm_step<2, false><<<dim3(32, 16), lb, 0, stream>>>(
        H0[0], Wih1c, H1[1], Whh1c, nullptr, bs1c, nullptr, 0, c1, H1[0]);

    // ----- decoder: s = 0..31.
    for (int s = 0; s < FWIN; ++s) {
        const float* xA = (s == 0) ? (x + (size_t)(TSTEPS - 1) * FINP)
                                   : (out + (size_t)(s - 1) * FINP);
        int sx = (s == 0) ? (TSTEPS * FINP) : (FWIN * FINP);
        lstm_step<1, true><<<dim3(32, 16), lb, 0, stream>>>(
            H0[s & 1], Whh0c, nullptr, nullptr, Wf0c, bf0c, xA, sx, c0, H0[(s + 1) & 1]);
        lstm_step<2, false><<<dim3(32, 16), lb, 0, stream>>>(
            H0[(s + 1) & 1], Wih1c, H1[s & 1], Whh1c, nullptr, bs1c, nullptr, 0,
            c1, H1[(s + 1) & 1]);
        fc1_mfma<<<dim3(32, 4), lb, 0, stream>>>(H1[(s + 1) & 1], fc1wb, fc1b, Z);
        ln_fc2_kernel<<<NB / 4, 256, 0, stream>>>(Z, lng, lnb, fc2w, fc2b,
                                                  out + (size_t)s * FINP);
    }
}

// Round 8
// 5995.807 us; speedup vs baseline: 1.3931x; 1.3578x over previous
//
#include <hip/hip_runtime.h>
#include <math.h>

#define NB   4096
#define HID  512
#define G4H  2048
#define EDIM 256
#define FINP 8
#define TSTEPS 64
#define FWIN 32

typedef __bf16 bf16;
typedef bf16  bf16x8 __attribute__((ext_vector_type(8)));
typedef float f32x4  __attribute__((ext_vector_type(4)));

__device__ __forceinline__ float sigf(float x) { return 1.0f / (1.0f + __expf(-x)); }
__device__ __forceinline__ float tanhf_(float x) { return 2.0f * sigf(2.0f * x) - 1.0f; }

__device__ __forceinline__ void gload16(const void* g, void* l) {
    __builtin_amdgcn_global_load_lds((const __attribute__((address_space(1))) void*)g,
                                     (__attribute__((address_space(3))) void*)l, 16, 0, 0);
}

// Bijective XCD-chunked swizzle (nwg % 8 == 0; gridDim.x == 32)
__device__ __forceinline__ void swz32(int& bx, int& by) {
    int nwg  = (int)(gridDim.x * gridDim.y);
    int orig = (int)(blockIdx.x + blockIdx.y * gridDim.x);
    int swz  = (orig & 7) * (nwg >> 3) + (orig >> 3);
    bx = swz & 31;
    by = swz >> 5;
}

// ---------------------------------------------------------------------------
// 128x128-tile bf16 MFMA accumulate over npass*512 K.
// LDS chunk layout (per 8KB buffer, 512 x 16B chunks): chunk s holds
//   A[row = s>>2][8 bf16 at col ((s&3) ^ ((s>>3)&3))*8]
// Write side (global_load_lds, dst linear tid*16): threads 4t..4t+3 source
//   one row's contiguous 64B (XOR permutes within it) -> coalescing = R3.
// Read side: frag addr = row*32 + (koct ^ ((row>>1)&3))*8 elements; per
//   16-lane group bank-quad (4*l16 + (l16>>1&3))%8 hits all 8 -> 2 lanes/bank
//   (free, m136). R6/R7's fragment-major layout had conflict-free reads but
//   64x16B scattered VMEM per wave (4x requests) -> 68->90us regression.
// Loop: 1 __syncthreads per iter, double-buffered prefetch.
// 256 threads = 4 waves (2x2 of 64x64). A,W row-major ld=512.
// ---------------------------------------------------------------------------
__device__ __forceinline__ void gemm_acc(
    const bf16* __restrict__ A1, const bf16* __restrict__ W1,
    const bf16* __restrict__ A2, const bf16* __restrict__ W2, int npass,
    int m0, int n0, bf16 (&As)[2][4096], bf16 (&Ws)[2][4096], f32x4 (&acc)[4][4])
{
    const int tid  = threadIdx.x;
    const int lane = tid & 63;
    const int w    = tid >> 6;
    const int wr   = w >> 1, wc = w & 1;
    const int l16  = lane & 15;
    const int NK   = npass << 4;

    // staging: thread covers chunks tid (rows 0..63) and tid+256 (rows 64..127)
    const int r0 = tid >> 2;
    const int o0 = ((tid & 3) ^ ((tid >> 3) & 3)) * 8;   // XOR col swizzle

    auto stage = [&](int s, int b) {
        const bf16* A = (s < 16) ? A1 : A2;
        const bf16* W = (s < 16) ? W1 : W2;
        const int k0 = ((s & 15) << 5) + o0;
        gload16(A + (size_t)(m0 + r0) * HID + k0,      &As[b][tid * 8]);
        gload16(A + (size_t)(m0 + r0 + 64) * HID + k0, &As[b][(tid + 256) * 8]);
        gload16(W + (size_t)(n0 + r0) * HID + k0,      &Ws[b][tid * 8]);
        gload16(W + (size_t)(n0 + r0 + 64) * HID + k0, &Ws[b][(tid + 256) * 8]);
    };

    // read offsets: row = wr*64 + m*16 + l16, koct = lane>>4 (XOR-swizzled)
    const int swz_k = (((lane >> 4) ^ ((l16 >> 1) & 3))) * 8;
    const int aoff = wr * 2048 + l16 * 32 + swz_k;
    const int boff = wc * 2048 + l16 * 32 + swz_k;

    stage(0, 0);
    __syncthreads();                              // buf0 ready (vmcnt drained)
    int cur = 0;
    for (int s = 0; s < NK; ++s) {
        if (s + 1 < NK) stage(s + 1, cur ^ 1);    // prefetch overlaps compute
        const bf16* ap = &As[cur][aoff];
        const bf16* bp = &Ws[cur][boff];
        bf16x8 af[4], bfr[4];
#pragma unroll
        for (int m = 0; m < 4; ++m) af[m] = *(const bf16x8*)(ap + m * 512);
#pragma unroll
        for (int n = 0; n < 4; ++n) bfr[n] = *(const bf16x8*)(bp + n * 512);
#pragma unroll
        for (int m = 0; m < 4; ++m)
#pragma unroll
            for (int n = 0; n < 4; ++n)
                acc[m][n] = __builtin_amdgcn_mfma_f32_16x16x32_bf16(af[m], bfr[n], acc[m][n], 0, 0, 0);
        __syncthreads();                          // drain prefetch + all reads done
        cur ^= 1;
    }
}

// ---------------------------------------------------------------------------
// LSTM epilogue. Weight rows pre-reordered: j_new = (hu>>4)*64 + gate*16 +
// (hu&15) -> wave's 4 N-frags are gates i,f,g,o of 16 hus (lane-local).
// ---------------------------------------------------------------------------
template<bool HASX>
__device__ __forceinline__ void lstm_epi(f32x4 (&acc)[4][4],
    const float* __restrict__ Wfc, const float* __restrict__ bias,
    const float* __restrict__ xA, int sx,
    float* __restrict__ cst, bf16* __restrict__ hdst, int m0, int n0)
{
    const int tid = threadIdx.x, lane = tid & 63, w = tid >> 6;
    const int wr = w >> 1, wc = w & 1, l16 = lane & 15, lq = lane >> 4;
    const int hu = (n0 >> 2) + wc * 16 + l16;
    const int jb = n0 + wc * 64 + l16;

    float bq[4];
    f32x4 wf0[4], wf1[4];
#pragma unroll
    for (int g = 0; g < 4; ++g) {
        bq[g] = bias[jb + g * 16];
        if constexpr (HASX) {
            const float* wrow = Wfc + (size_t)(jb + g * 16) * 8;
            wf0[g] = *(const f32x4*)wrow;
            wf1[g] = *(const f32x4*)(wrow + 4);
        }
    }
#pragma unroll
    for (int m = 0; m < 4; ++m) {
        const int rb = m0 + wr * 64 + m * 16 + lq * 4;
#pragma unroll
        for (int q = 0; q < 4; ++q) {
            const int r = rb + q;
            float d0 = 0.f, d1 = 0.f, d2 = 0.f, d3 = 0.f;
            if constexpr (HASX) {
                const float* xr = xA + (size_t)r * sx;
                f32x4 xv0 = *(const f32x4*)xr;
                f32x4 xv1 = *(const f32x4*)(xr + 4);
                f32x4 p0 = xv0 * wf0[0] + xv1 * wf1[0];
                f32x4 p1 = xv0 * wf0[1] + xv1 * wf1[1];
                f32x4 p2 = xv0 * wf0[2] + xv1 * wf1[2];
                f32x4 p3 = xv0 * wf0[3] + xv1 * wf1[3];
                d0 = p0[0] + p0[1] + p0[2] + p0[3];
                d1 = p1[0] + p1[1] + p1[2] + p1[3];
                d2 = p2[0] + p2[1] + p2[2] + p2[3];
                d3 = p3[0] + p3[1] + p3[2] + p3[3];
            }
            float gi = acc[m][0][q] + bq[0] + d0;
            float gf = acc[m][1][q] + bq[1] + d1;
            float gg = acc[m][2][q] + bq[2] + d2;
            float go = acc[m][3][q] + bq[3] + d3;
            float iv = sigf(gi), fv = sigf(gf), gv = tanhf_(gg), ov = sigf(go);
            size_t ci = (size_t)r * HID + hu;
            float cn = fv * cst[ci] + iv * gv;
            cst[ci] = cn;
            hdst[ci] = (bf16)(ov * tanhf_(cn));
        }
    }
}

// ---------------------------------------------------------------------------
// Standalone LSTM cell (decoder + encoder-final). grid (32,16).
// ---------------------------------------------------------------------------
template<int NPASS, bool HASX>
__global__ __launch_bounds__(256)
void lstm_step(const bf16* __restrict__ A1, const bf16* __restrict__ W1,
               const bf16* __restrict__ A2, const bf16* __restrict__ W2,
               const float* __restrict__ Wfc, const float* __restrict__ bias,
               const float* __restrict__ xA, int sx,
               float* __restrict__ cst, bf16* __restrict__ hdst)
{
    __shared__ __align__(16) bf16 As[2][4096], Ws[2][4096];
    int bx, by; swz32(bx, by);
    const int m0 = bx * 128, n0 = by * 128;
    f32x4 acc[4][4];
#pragma unroll
    for (int m = 0; m < 4; ++m)
#pragma unroll
        for (int n = 0; n < 4; ++n) acc[m][n] = (f32x4){0.f, 0.f, 0.f, 0.f};
    gemm_acc(A1, W1, A2, W2, NPASS, m0, n0, As, Ws, acc);
    lstm_epi<HASX>(acc, Wfc, bias, xA, sx, cst, hdst, m0, n0);
}

// ---------------------------------------------------------------------------
// Fused encoder step: layer0[t+1] || layer1[t], grid (32,32).
// BALANCED mapping: layer = swz&1 -> each XCD chunk of 128 blocks gets 64
// short (1-pass) + 64 long (2-pass) blocks.
// ---------------------------------------------------------------------------
template<bool L1TWO>
__global__ __launch_bounds__(256)
void enc_fused(const bf16* __restrict__ h0_in, const bf16* __restrict__ Whh0c,
               const float* __restrict__ Wf0c, const float* __restrict__ bf0c,
               const float* __restrict__ xA,
               bf16* __restrict__ h0_out, float* __restrict__ c0,
               const bf16* __restrict__ Wih1c, const bf16* __restrict__ h1_in,
               const bf16* __restrict__ Whh1c, const float* __restrict__ bs1c,
               bf16* __restrict__ h1_out, float* __restrict__ c1)
{
    __shared__ __align__(16) bf16 As[2][4096], Ws[2][4096];
    int orig = (int)(blockIdx.x + blockIdx.y * gridDim.x);    // 0..1023
    int swz  = (orig & 7) * 128 + (orig >> 3);                // XCD-chunked
    int layer = swz & 1;
    int rest  = swz >> 1;                                     // 0..511
    const int m0 = (rest & 31) * 128;
    const int n0 = (rest >> 5) * 128;
    f32x4 acc[4][4];
#pragma unroll
    for (int m = 0; m < 4; ++m)
#pragma unroll
        for (int n = 0; n < 4; ++n) acc[m][n] = (f32x4){0.f, 0.f, 0.f, 0.f};
    if (layer == 0) {
        gemm_acc(h0_in, Whh0c, nullptr, nullptr, 1, m0, n0, As, Ws, acc);
        lstm_epi<true>(acc, Wf0c, bf0c, xA, TSTEPS * FINP, c0, h0_out, m0, n0);
    } else {
        gemm_acc(h0_in, Wih1c, h1_in, Whh1c, L1TWO ? 2 : 1, m0, n0, As, Ws, acc);
        lstm_epi<false>(acc, nullptr, bs1c, nullptr, 0, c1, h1_out, m0, n0);
    }
}

// ---------------------------------------------------------------------------
// Encoder step 0 (h=0, c=0): epilogue-only. grid 8192 x 256.
// ---------------------------------------------------------------------------
__global__ __launch_bounds__(256)
void init_step(const float* __restrict__ x, const float* __restrict__ Wf0c,
               const float* __restrict__ bf0c, bf16* __restrict__ h0,
               float* __restrict__ c0)
{
    int idx = blockIdx.x * 256 + threadIdx.x;     // = r*512 + hu
    int r = idx >> 9, hu = idx & 511;
    const float* xr = x + (size_t)r * (TSTEPS * FINP);
    f32x4 xv0 = *(const f32x4*)xr;
    f32x4 xv1 = *(const f32x4*)(xr + 4);
    int jb = ((hu >> 4) << 6) + (hu & 15);
    float g[4];
#pragma unroll
    for (int gg = 0; gg < 4; ++gg) {
        const float* wrow = Wf0c + (size_t)(jb + gg * 16) * 8;
        f32x4 w0 = *(const f32x4*)wrow;
        f32x4 w1 = *(const f32x4*)(wrow + 4);
        f32x4 p = xv0 * w0 + xv1 * w1;
        g[gg] = bf0c[jb + gg * 16] + p[0] + p[1] + p[2] + p[3];
    }
    float iv = sigf(g[0]), gv = tanhf_(g[2]), ov = sigf(g[3]);
    float cn = iv * gv;                            // c_prev = 0
    c0[idx] = cn;
    h0[idx] = (bf16)(ov * tanhf_(cn));
}

// ---------------------------------------------------------------------------
// fc1: Z = A @ W^T + b (fp32 out). grid (32,4).
// ---------------------------------------------------------------------------
__global__ __launch_bounds__(256)
void fc1_mfma(const bf16* __restrict__ A, const bf16* __restrict__ W,
              const float* __restrict__ bias, float* __restrict__ Z)
{
    __shared__ __align__(16) bf16 As[2][4096], Ws[2][4096];
    int bx, by; swz32(bx, by);
    const int m0 = bx * 128, n0 = by * 128;
    f32x4 acc[4][4];
#pragma unroll
    for (int m = 0; m < 4; ++m)
#pragma unroll
        for (int n = 0; n < 4; ++n) acc[m][n] = (f32x4){0.f, 0.f, 0.f, 0.f};
    gemm_acc(A, W, nullptr, nullptr, 1, m0, n0, As, Ws, acc);

    const int tid = threadIdx.x, lane = tid & 63, w = tid >> 6;
    const int wr = w >> 1, wc = w & 1, l16 = lane & 15, lq = lane >> 4;
#pragma unroll
    for (int m = 0; m < 4; ++m) {
        const int rb = m0 + wr * 64 + m * 16 + lq * 4;
#pragma unroll
        for (int n = 0; n < 4; ++n) {
            const int col = n0 + wc * 64 + n * 16 + l16;
            float bv = bias[col];
#pragma unroll
            for (int q = 0; q < 4; ++q)
                Z[(size_t)(rb + q) * HID + col] = acc[m][n][q] + bv;
        }
    }
}

// ---------------------------------------------------------------------------
// LayerNorm + ReLU + fc2 (8 outs), one wave per row.
// ---------------------------------------------------------------------------
__global__ __launch_bounds__(256)
void ln_fc2_kernel(const float* __restrict__ Z, const float* __restrict__ lng,
                   const float* __restrict__ lnb, const float* __restrict__ w2,
                   const float* __restrict__ b2, float* __restrict__ out)
{
    int wave = threadIdx.x >> 6;
    int lane = threadIdx.x & 63;
    int n = blockIdx.x * 4 + wave;
    const float* zr = Z + (size_t)n * HID;

    float v[8];
    float s1 = 0.f, s2 = 0.f;
#pragma unroll
    for (int j = 0; j < 8; ++j) {
        v[j] = zr[lane + j * 64];
        s1 += v[j];
        s2 += v[j] * v[j];
    }
#pragma unroll
    for (int off = 32; off; off >>= 1) {
        s1 += __shfl_down(s1, off);
        s2 += __shfl_down(s2, off);
    }
    s1 = __shfl(s1, 0);
    s2 = __shfl(s2, 0);
    float mu = s1 * (1.f / 512.f);
    float var = s2 * (1.f / 512.f) - mu * mu;
    float rs = rsqrtf(var + 1e-5f);

    float y[8];
#pragma unroll
    for (int f = 0; f < 8; ++f) y[f] = 0.f;
#pragma unroll
    for (int j = 0; j < 8; ++j) {
        int h = lane + j * 64;
        float zn = (v[j] - mu) * rs * lng[h] + lnb[h];
        zn = fmaxf(zn, 0.f);
#pragma unroll
        for (int f = 0; f < 8; ++f) y[f] += zn * w2[f * HID + h];
    }
#pragma unroll
    for (int f = 0; f < 8; ++f)
#pragma unroll
        for (int off = 32; off; off >>= 1) y[f] += __shfl_down(y[f], off);

    if (lane == 0) {
#pragma unroll
        for (int f = 0; f < 8; ++f) out[(size_t)n * 256 + f] = y[f] + b2[f];
    }
}

// ---------------------------------------------------------------------------
// Weight preprocessing
// ---------------------------------------------------------------------------
__device__ __forceinline__ int remap_j(int j) {
    int gate = j >> 9, hu = j & 511;
    return ((hu >> 4) << 6) + (gate << 4) + (hu & 15);
}

__global__ void fold_small(const float* __restrict__ Wih0, const float* __restrict__ We,
                           const float* __restrict__ be, const float* __restrict__ bih0,
                           const float* __restrict__ bhh0, const float* __restrict__ bih1,
                           const float* __restrict__ bhh1,
                           float* __restrict__ Wf0c, float* __restrict__ bf0c,
                           float* __restrict__ bs1c)
{
    int j = blockIdx.x * 256 + threadIdx.x;
    if (j >= G4H) return;
    int jn = remap_j(j);
    float acc[FINP];
#pragma unroll
    for (int f = 0; f < FINP; ++f) acc[f] = 0.f;
    float bacc = 0.f;
    for (int e = 0; e < EDIM; ++e) {
        float wv = Wih0[(size_t)j * EDIM + e];
        bacc += wv * be[e];
#pragma unroll
        for (int f = 0; f < FINP; ++f) acc[f] += wv * We[e * FINP + f];
    }
#pragma unroll
    for (int f = 0; f < FINP; ++f) Wf0c[(size_t)jn * FINP + f] = acc[f];
    bf0c[jn] = bacc + bih0[j] + bhh0[j];
    bs1c[jn] = bih1[j] + bhh1[j];
}

__global__ void conv_w(const float* __restrict__ W0, const float* __restrict__ W1,
                       const float* __restrict__ W2,
                       bf16* __restrict__ O0, bf16* __restrict__ O1, bf16* __restrict__ O2)
{
    int j = blockIdx.x;
    int which = blockIdx.y;
    const float* src = which == 0 ? W0 : which == 1 ? W1 : W2;
    bf16* dst = which == 0 ? O0 : which == 1 ? O1 : O2;
    int jn = remap_j(j);
    for (int k = threadIdx.x; k < HID; k += 256)
        dst[(size_t)jn * HID + k] = (bf16)src[(size_t)j * HID + k];
}

__global__ void conv_fc1(const float* __restrict__ W, bf16* __restrict__ O)
{
    int j = blockIdx.x;
    for (int k = threadIdx.x; k < HID; k += 256)
        O[(size_t)j * HID + k] = (bf16)W[(size_t)j * HID + k];
}

// ---------------------------------------------------------------------------
extern "C" void kernel_launch(void* const* d_in, const int* in_sizes, int n_in,
                              void* d_out, int out_size, void* d_ws, size_t ws_size,
                              hipStream_t stream)
{
    const float* x    = (const float*)d_in[0];
    const float* We   = (const float*)d_in[1];
    const float* be   = (const float*)d_in[2];
    const float* Wih0 = (const float*)d_in[3];
    const float* Whh0 = (const float*)d_in[4];
    const float* bih0 = (const float*)d_in[5];
    const float* bhh0 = (const float*)d_in[6];
    const float* Wih1 = (const float*)d_in[7];
    const float* Whh1 = (const float*)d_in[8];
    const float* bih1 = (const float*)d_in[9];
    const float* bhh1 = (const float*)d_in[10];
    const float* fc1w = (const float*)d_in[11];
    const float* fc1b = (const float*)d_in[12];
    const float* lng  = (const float*)d_in[13];
    const float* lnb  = (const float*)d_in[14];
    const float* fc2w = (const float*)d_in[15];
    const float* fc2b = (const float*)d_in[16];
    float* out = (float*)d_out;

    char* p = (char*)d_ws;
    auto alloc = [&](size_t bytes) -> void* {
        void* r = (void*)p;
        p += (bytes + 255) & ~(size_t)255;
        return r;
    };
    bf16*  Whh0c = (bf16*)alloc((size_t)G4H * HID * 2);
    bf16*  Wih1c = (bf16*)alloc((size_t)G4H * HID * 2);
    bf16*  Whh1c = (bf16*)alloc((size_t)G4H * HID * 2);
    bf16*  fc1wb = (bf16*)alloc((size_t)HID * HID * 2);
    float* Wf0c  = (float*)alloc((size_t)G4H * FINP * 4);
    float* bf0c  = (float*)alloc((size_t)G4H * 4);
    float* bs1c  = (float*)alloc((size_t)G4H * 4);
    const size_t S = (size_t)NB * HID;
    bf16*  H0[2]; H0[0] = (bf16*)alloc(S * 2); H0[1] = (bf16*)alloc(S * 2);
    bf16*  H1[2]; H1[0] = (bf16*)alloc(S * 2); H1[1] = (bf16*)alloc(S * 2);
    float* c0    = (float*)alloc(S * 4);
    float* c1    = (float*)alloc(S * 4);
    float* Z     = (float*)alloc(S * 4);

    hipMemsetAsync(c1, 0, S * 4, stream);   // layer1[0] epilogue reads c1

    fold_small<<<8, 256, 0, stream>>>(Wih0, We, be, bih0, bhh0, bih1, bhh1, Wf0c, bf0c, bs1c);
    conv_w<<<dim3(G4H, 3), 256, 0, stream>>>(Whh0, Wih1, Whh1, Whh0c, Wih1c, Whh1c);
    conv_fc1<<<HID, 256, 0, stream>>>(fc1w, fc1wb);

    // ----- encoder: t = 0..62 (63 steps). h0[t] in H0[t&1], h1[t] in H1[t&1].
    init_step<<<NB * HID / 256, 256, 0, stream>>>(x, Wf0c, bf0c, H0[0], c0);

    dim3 fg(32, 32), lb(256);
    for (int t = 0; t < TSTEPS - 2; ++t) {   // t = 0..61: layer0[t+1] || layer1[t]
        if (t == 0)
            enc_fused<false><<<fg, lb, 0, stream>>>(H0[0], Whh0c, Wf0c, bf0c,
                x + (size_t)1 * FINP, H0[1], c0,
                Wih1c, nullptr, Whh1c, bs1c, H1[0], c1);
        else
            enc_fused<true><<<fg, lb, 0, stream>>>(H0[t & 1], Whh0c, Wf0c, bf0c,
                x + (size_t)(t + 1) * FINP, H0[(t + 1) & 1], c0,
                Wih1c, H1[(t + 1) & 1], Whh1c, bs1c, H1[t & 1], c1);
    }
    // final layer1[62]: reads h0[62]=H0[0], h1[61]=H1[1], writes H1[0]
    lstm_step<2, false><<<dim3(32, 16), lb, 0, stream>>>(
        H0[0], Wih1c, H1[1], Whh1c, nullptr, bs1c, nullptr, 0, c1, H1[0]);

    // ----- decoder: s = 0..31.
    for (int s = 0; s < FWIN; ++s) {
        const float* xA = (s == 0) ? (x + (size_t)(TSTEPS - 1) * FINP)
                                   : (out + (size_t)(s - 1) * FINP);
        int sx = (s == 0) ? (TSTEPS * FINP) : (FWIN * FINP);
        lstm_step<1, true><<<dim3(32, 16), lb, 0, stream>>>(
            H0[s & 1], Whh0c, nullptr, nullptr, Wf0c, bf0c, xA, sx, c0, H0[(s + 1) & 1]);
        lstm_step<2, false><<<dim3(32, 16), lb, 0, stream>>>(
            H0[(s + 1) & 1], Wih1c, H1[s & 1], Whh1c, nullptr, bs1c, nullptr, 0,
            c1, H1[(s + 1) & 1]);
        fc1_mfma<<<dim3(32, 4), lb, 0, stream>>>(H1[(s + 1) & 1], fc1wb, fc1b, Z);
        ln_fc2_kernel<<<NB / 4, 256, 0, stream>>>(Z, lng, lnb, fc2w, fc2b,
                                                  out + (size_t)s * FINP);
    }
}